// Round 9
// baseline (503.110 us; speedup 1.0000x reference)
//
#include <hip/hip_runtime.h>
#include <hip/hip_bf16.h>

// Problem constants
#define BB 8
#define NN 1024
#define DD 256
#define HH 8
#define DK 32
#define FFN 1024
#define NLAYERS 4
#define MM (BB * NN)          // 8192 rows
#define ROW_ELEMS (MM * DD)   // 2,097,152

typedef unsigned short ushort_t;
typedef __attribute__((ext_vector_type(8))) short bf16x8;
typedef __attribute__((ext_vector_type(4))) float f32x4;

__device__ __forceinline__ ushort_t f2b(float f) {
    __hip_bfloat16 h = __float2bfloat16(f);
    return *reinterpret_cast<ushort_t*>(&h);
}

// async global -> LDS, 16 B per lane. LDS dest = wave-uniform base + lane*16B.
__device__ __forceinline__ void async_ld16(const void* g, void* l) {
    __builtin_amdgcn_global_load_lds((const __attribute__((address_space(1))) void*)g,
                                     (__attribute__((address_space(3))) void*)l, 16, 0, 0);
}

// ---------------------------------------------------------------------------
// copy-in: x -> xf (f32) + xb (bf16)
// ---------------------------------------------------------------------------
__global__ __launch_bounds__(256) void copy_in_kernel(const float* __restrict__ in,
                                                      float* __restrict__ xf,
                                                      ushort_t* __restrict__ xb, int n) {
    int i = blockIdx.x * 256 + threadIdx.x;
    if (i < n) { float v = in[i]; xf[i] = v; xb[i] = f2b(v); }
}

// ---------------------------------------------------------------------------
// Fused weight prep: all 5 transposes (f32 [R][C] -> bf16 [C][R]) + bias
// concat in ONE dispatch. Block id encodes (layer, which-weight, tile).
// Per layer: 64 tiles x3 (Wq,Wk,Wv) + 256 (W1) + 256 (W2) + 3 bias chunks = 707.
// ---------------------------------------------------------------------------
__global__ __launch_bounds__(256) void prep_kernel(const float* __restrict__ Wq,
                                                   const float* __restrict__ Wk,
                                                   const float* __restrict__ Wv,
                                                   const float* __restrict__ W1,
                                                   const float* __restrict__ W2,
                                                   const float* __restrict__ bq,
                                                   const float* __restrict__ bk,
                                                   const float* __restrict__ bv,
                                                   ushort_t* __restrict__ wqkvt,
                                                   ushort_t* __restrict__ w1t,
                                                   ushort_t* __restrict__ w2t,
                                                   float* __restrict__ bqkv) {
    const int id = blockIdx.x;
    const int layer = id / 707;
    const int r = id % 707;
    const int tid = threadIdx.x;

    if (r >= 704) {  // bias concat: 3 chunks of 256
        const int chunk = r - 704;
        const float* src = (chunk == 0) ? bq : (chunk == 1) ? bk : bv;
        bqkv[layer * 768 + chunk * 256 + tid] = src[layer * 256 + tid];
        return;
    }

    const float* src;
    ushort_t* dst;
    int R, C, x, y;
    if (r < 192) {
        const int w = r >> 6, rr = r & 63;
        src = ((w == 0) ? Wq : (w == 1) ? Wk : Wv) + (size_t)layer * 65536;
        dst = wqkvt + (size_t)layer * 196608 + w * 65536;
        R = 256; C = 256; x = rr & 7; y = rr >> 3;
    } else if (r < 448) {
        const int rr = r - 192;
        src = W1 + (size_t)layer * 262144;
        dst = w1t + (size_t)layer * 262144;
        R = 256; C = 1024; x = rr & 31; y = rr >> 5;
    } else {
        const int rr = r - 448;
        src = W2 + (size_t)layer * 262144;
        dst = w2t + (size_t)layer * 262144;
        R = 1024; C = 256; x = rr & 7; y = rr >> 3;
    }
    const int r0 = y * 32, c0 = x * 32;
    __shared__ float tile[32][33];
    const int tx = tid & 31, ty = tid >> 5;
#pragma unroll
    for (int i = 0; i < 4; ++i)
        tile[ty + 8 * i][tx] = src[(size_t)(r0 + ty + 8 * i) * C + (c0 + tx)];
    __syncthreads();
#pragma unroll
    for (int i = 0; i < 4; ++i)
        dst[(size_t)(c0 + ty + 8 * i) * R + (r0 + tx)] = f2b(tile[tx][ty + 8 * i]);
}

// ---------------------------------------------------------------------------
// MFMA bf16 GEMM, async global_load_lds staging (16B). (unchanged, round 8)
// MODE 0: f32 out. MODE 1: relu + bf16 out. MODE 2: QKV scatter epilogue into
// Qa[bh][n][64] (x scale, + alpha*coords in dims 32..34), Ka[bh][n][64]
// (+ coords in dims 32..34), Vt[bh][d][n].
// ---------------------------------------------------------------------------
template <int MODE, int BM>
__global__ __launch_bounds__(256) void mfma_gemm_kernel(const ushort_t* __restrict__ A,
                                                        const ushort_t* __restrict__ Bt,
                                                        const float* __restrict__ bias,
                                                        void* __restrict__ C0,
                                                        void* __restrict__ C1,
                                                        void* __restrict__ C2,
                                                        const float* __restrict__ coords,
                                                        const float* __restrict__ alpha, int layer,
                                                        int K, int ldc) {
    constexpr int NI = BM / 32;
    __shared__ ushort_t As[BM * 32];
    __shared__ ushort_t Bs[128 * 32];

    const int t    = threadIdx.x;
    const int bm   = blockIdx.y * BM;
    const int bn   = blockIdx.x * 128;
    const int wave = t >> 6, lane = t & 63;
    const int wm   = (wave >> 1) * (BM / 2), wn = (wave & 1) * 64;
    const int quad = lane >> 4, l16 = lane & 15;

    const int srow = t >> 2;
    const int scol = (t & 3) * 8;

    f32x4 acc[NI][4];
#pragma unroll
    for (int i = 0; i < NI; ++i)
#pragma unroll
        for (int j = 0; j < 4; ++j) {
            f32x4 z = {0.f, 0.f, 0.f, 0.f};
            acc[i][j] = z;
        }

    for (int k0 = 0; k0 < K; k0 += 32) {
        __syncthreads();
        async_ld16(A + (size_t)(bm + srow) * K + k0 + scol, As + wave * 512);
        if constexpr (BM == 128)
            async_ld16(A + (size_t)(bm + 64 + srow) * K + k0 + scol, As + 2048 + wave * 512);
        async_ld16(Bt + (size_t)(bn + srow) * K + k0 + scol, Bs + wave * 512);
        async_ld16(Bt + (size_t)(bn + 64 + srow) * K + k0 + scol, Bs + 2048 + wave * 512);
        __syncthreads();

        bf16x8 af[NI], bfr[4];
#pragma unroll
        for (int i = 0; i < NI; ++i)
            af[i] = *(const bf16x8*)(As + (wm + i * 16 + l16) * 32 + quad * 8);
#pragma unroll
        for (int j = 0; j < 4; ++j)
            bfr[j] = *(const bf16x8*)(Bs + (wn + j * 16 + l16) * 32 + quad * 8);
#pragma unroll
        for (int i = 0; i < NI; ++i)
#pragma unroll
            for (int j = 0; j < 4; ++j)
                acc[i][j] = __builtin_amdgcn_mfma_f32_16x16x32_bf16(af[i], bfr[j], acc[i][j], 0, 0, 0);
    }

    const float av = (MODE == 2) ? alpha[layer] : 0.f;

#pragma unroll
    for (int j = 0; j < 4; ++j) {
        const int col = bn + wn + j * 16 + l16;
        const float bsv = bias[col];
#pragma unroll
        for (int i = 0; i < NI; ++i) {
            const int row0 = bm + wm + i * 16 + quad * 4;
#pragma unroll
            for (int r = 0; r < 4; ++r) {
                float v = acc[i][j][r] + bsv;
                if (MODE == 0) {
                    ((float*)C0)[(size_t)(row0 + r) * ldc + col] = v;
                } else if (MODE == 1) {
                    ((ushort_t*)C0)[(size_t)(row0 + r) * ldc + col] = f2b(fmaxf(v, 0.f));
                } else {
                    const int row = row0 + r;
                    const int bb2 = row >> 10, nn = row & 1023;
                    const int which = col >> 8, rem = col & 255;
                    const int h = rem >> 5, d = rem & 31;
                    const size_t bh = (size_t)((bb2 << 3) + h);
                    if (which == 0) {
                        ((ushort_t*)C0)[(bh * NN + nn) * 64 + d] = f2b(v * 0.17677669529663687f);
                        ushort_t ext = 0;
                        if (d < 3) ext = f2b(av * coords[(size_t)(bb2 * NN + nn) * 3 + d]);
                        ((ushort_t*)C0)[(bh * NN + nn) * 64 + 32 + d] = ext;
                    } else if (which == 1) {
                        ((ushort_t*)C1)[(bh * NN + nn) * 64 + d] = f2b(v);
                        ushort_t ext = 0;
                        if (d < 3) ext = f2b(coords[(size_t)(bb2 * NN + nn) * 3 + d]);
                        ((ushort_t*)C1)[(bh * NN + nn) * 64 + 32 + d] = ext;
                    } else {
                        ((ushort_t*)C2)[(bh * DK + d) * NN + nn] = f2b(v);
                    }
                }
            }
        }
    }
}

// ---------------------------------------------------------------------------
// MFMA flash attention v3 — wave-private key-split.
// Grid (8,8,8), block 256 = 4 waves. Block owns 128 q-rows; wave w owns the
// DISJOINT key quarter [w*256, w*256+256). No-max softmax partials over
// disjoint key sets combine exactly (validated rounds 4-8). Each wave stages
// its K/V tiles into PRIVATE LDS -> zero __syncthreads in the main loop, and
// K/V fragment reads drop 4x vs the shared-tile scheme. P roundtrips through
// double-buffered per-wave LDS (no post-read waitcnt). At the end the 4
// partial (O, l) merge through LDS (re-aliased over K/V/P buffers).
// ---------------------------------------------------------------------------
__global__ __launch_bounds__(256, 2) void attn5_kernel(const ushort_t* __restrict__ Qa,
                                                       const ushort_t* __restrict__ Ka,
                                                       const ushort_t* __restrict__ Vt,
                                                       float* __restrict__ aout) {
    const int b = blockIdx.z, h = blockIdx.y, n0 = blockIdx.x * 128;
    const int t = threadIdx.x, wave = t >> 6, lane = t & 63;
    const int quad = lane >> 4, l16 = lane & 15;
    const int bh = b * HH + h;

    __shared__ __align__(16) char smem[75776];
    ushort_t (*Ks)[64][72]    = (ushort_t (*)[64][72])smem;              // [4] 36864 B
    ushort_t (*Vs)[32][72]    = (ushort_t (*)[32][72])(smem + 36864);    // [4] 18432 B
    ushort_t (*Ps)[2][16][72] = (ushort_t (*)[2][16][72])(smem + 55296); // [4] 18432 B
    float    (*Om)[128][36]   = (float (*)[128][36])smem;                // [4] merge alias
    float    (*Lm)[128]       = (float (*)[128])(smem + 73728);          // 2048 B

    // Q fragments: 8 subtiles of 16 q-rows (whole block's 128 q, per wave)
    bf16x8 aq[8][2];
#pragma unroll
    for (int s = 0; s < 8; ++s) {
        const ushort_t* qp = Qa + ((size_t)bh * NN + n0 + s * 16 + l16) * 64 + quad * 8;
        aq[s][0] = *(const bf16x8*)qp;
        aq[s][1] = *(const bf16x8*)(qp + 32);
    }

    bf16x8 ones;
#pragma unroll
    for (int i = 0; i < 8; ++i) ones[i] = (short)0x3F80;  // bf16 1.0

    const f32x4 z = {0.f, 0.f, 0.f, 0.f};
    f32x4 acc_o0[8], acc_o1[8], acc_l[8];
#pragma unroll
    for (int s = 0; s < 8; ++s) { acc_o0[s] = z; acc_o1[s] = z; acc_l[s] = z; }

    const ushort_t* kg = Ka + ((size_t)bh * NN + wave * 256) * 64;
    const ushort_t* vg = Vt + (size_t)bh * DK * NN + wave * 256;

    const int srow = lane >> 3, sch = (lane & 7) * 8;   // staging: 8 rows x 8 chunks

    for (int kt = 0; kt < 4; ++kt) {
        // stage this wave's 64-key K tile (64x64) and V tile (32x64) privately
#pragma unroll
        for (int i = 0; i < 8; ++i) {
            uint4 kv = *(const uint4*)(kg + (size_t)(kt * 64 + i * 8 + srow) * 64 + sch);
            *(uint4*)&Ks[wave][i * 8 + srow][sch] = kv;
        }
#pragma unroll
        for (int i = 0; i < 4; ++i) {
            uint4 vv = *(const uint4*)(vg + (size_t)(i * 8 + srow) * NN + kt * 64 + sch);
            *(uint4*)&Vs[wave][i * 8 + srow][sch] = vv;
        }
        __builtin_amdgcn_s_waitcnt(0xC07F);   // lgkmcnt(0): staging writes visible
        __builtin_amdgcn_wave_barrier();

        bf16x8 bk0[4], bk1[4];
#pragma unroll
        for (int jt = 0; jt < 4; ++jt) {
            bk0[jt] = *(const bf16x8*)&Ks[wave][jt * 16 + l16][quad * 8];
            bk1[jt] = *(const bf16x8*)&Ks[wave][jt * 16 + l16][32 + quad * 8];
        }
        bf16x8 bv00 = *(const bf16x8*)&Vs[wave][l16][quad * 8];
        bf16x8 bv01 = *(const bf16x8*)&Vs[wave][l16][32 + quad * 8];
        bf16x8 bv10 = *(const bf16x8*)&Vs[wave][16 + l16][quad * 8];
        bf16x8 bv11 = *(const bf16x8*)&Vs[wave][16 + l16][32 + quad * 8];

#pragma unroll
        for (int s = 0; s < 8; ++s) {
            const int pb = s & 1;
            f32x4 sc[4];
#pragma unroll
            for (int jt = 0; jt < 4; ++jt) {
                sc[jt] = __builtin_amdgcn_mfma_f32_16x16x32_bf16(aq[s][0], bk0[jt], z, 0, 0, 0);
                sc[jt] = __builtin_amdgcn_mfma_f32_16x16x32_bf16(aq[s][1], bk1[jt], sc[jt], 0, 0, 0);
            }
#pragma unroll
            for (int jt = 0; jt < 4; ++jt)
#pragma unroll
                for (int r = 0; r < 4; ++r)
                    Ps[wave][pb][quad * 4 + r][jt * 16 + l16] = f2b(__expf(sc[jt][r]));

            __builtin_amdgcn_s_waitcnt(0xC07F);   // lgkmcnt(0): P writes visible
            __builtin_amdgcn_wave_barrier();

            bf16x8 pa0 = *(const bf16x8*)&Ps[wave][pb][l16][quad * 8];
            bf16x8 pa1 = *(const bf16x8*)&Ps[wave][pb][l16][32 + quad * 8];

            acc_o0[s] = __builtin_amdgcn_mfma_f32_16x16x32_bf16(pa0, bv00, acc_o0[s], 0, 0, 0);
            acc_o0[s] = __builtin_amdgcn_mfma_f32_16x16x32_bf16(pa1, bv01, acc_o0[s], 0, 0, 0);
            acc_o1[s] = __builtin_amdgcn_mfma_f32_16x16x32_bf16(pa0, bv10, acc_o1[s], 0, 0, 0);
            acc_o1[s] = __builtin_amdgcn_mfma_f32_16x16x32_bf16(pa1, bv11, acc_o1[s], 0, 0, 0);
            acc_l[s]  = __builtin_amdgcn_mfma_f32_16x16x32_bf16(pa0, ones, acc_l[s], 0, 0, 0);
            acc_l[s]  = __builtin_amdgcn_mfma_f32_16x16x32_bf16(pa1, ones, acc_l[s], 0, 0, 0);
        }
    }

    // ---- merge the 4 waves' disjoint-key partials ----
    __syncthreads();   // all waves done with Ks/Vs/Ps; re-alias as Om/Lm
#pragma unroll
    for (int s = 0; s < 8; ++s)
#pragma unroll
        for (int r = 0; r < 4; ++r) {
            const int q = s * 16 + quad * 4 + r;
            Om[wave][q][l16]      = acc_o0[s][r];
            Om[wave][q][16 + l16] = acc_o1[s][r];
            if (l16 == 0) Lm[wave][q] = acc_l[s][r];
        }
    __syncthreads();

    {
        const int q = t >> 1, dh = (t & 1) * 16;
        float l = Lm[0][q] + Lm[1][q] + Lm[2][q] + Lm[3][q];
        const float inv = 1.0f / l;
        float* op = aout + (size_t)(b * NN + n0 + q) * DD + h * DK + dh;
#pragma unroll
        for (int c = 0; c < 4; ++c) {
            float4 acc4 = {0.f, 0.f, 0.f, 0.f};
#pragma unroll
            for (int w = 0; w < 4; ++w) {
                float4 v = *(const float4*)&Om[w][q][dh + c * 4];
                acc4.x += v.x; acc4.y += v.y; acc4.z += v.z; acc4.w += v.w;
            }
            float4 o = {acc4.x * inv, acc4.y * inv, acc4.z * inv, acc4.w * inv};
            *(float4*)(op + c * 4) = o;
        }
    }
}

// ---------------------------------------------------------------------------
// xout = LayerNorm(x + delta) * g + be ; also writes bf16 xb. (round 8)
// ---------------------------------------------------------------------------
__global__ __launch_bounds__(256) void addln_kernel(const float* __restrict__ x,
                                                    ushort_t* __restrict__ xb,
                                                    const float* __restrict__ delta, int dstride,
                                                    const float* __restrict__ g,
                                                    const float* __restrict__ be,
                                                    float* __restrict__ xout) {
    const int row  = blockIdx.x * 4 + (threadIdx.x >> 6);
    const int lane = threadIdx.x & 63;
    const size_t base = (size_t)row * DD + lane * 4;

    float4 xv = *(const float4*)(x + base);
    float4 dl = *(const float4*)(delta + (size_t)row * dstride + lane * 4);
    float v0 = xv.x + dl.x, v1 = xv.y + dl.y, v2 = xv.z + dl.z, v3 = xv.w + dl.w;

    float s = v0 + v1 + v2 + v3;
#pragma unroll
    for (int off = 32; off; off >>= 1) s += __shfl_xor(s, off);
    const float mean = s * (1.0f / 256.0f);

    float d0 = v0 - mean, d1 = v1 - mean, d2 = v2 - mean, d3 = v3 - mean;
    float s2 = d0 * d0 + d1 * d1 + d2 * d2 + d3 * d3;
#pragma unroll
    for (int off = 32; off; off >>= 1) s2 += __shfl_xor(s2, off);
    const float rs = rsqrtf(s2 * (1.0f / 256.0f) + 1e-5f);

    float4 gv = *(const float4*)(g + lane * 4);
    float4 bv = *(const float4*)(be + lane * 4);
    float y0 = d0 * rs * gv.x + bv.x;
    float y1 = d1 * rs * gv.y + bv.y;
    float y2 = d2 * rs * gv.z + bv.z;
    float y3 = d3 * rs * gv.w + bv.w;

    float4 o = {y0, y1, y2, y3};
    *(float4*)(xout + base) = o;
    ushort4 ob = {f2b(y0), f2b(y1), f2b(y2), f2b(y3)};
    *(ushort4*)(xb + base) = ob;
}

// ---------------------------------------------------------------------------
// launch — workspace ~45.5 MB
// ---------------------------------------------------------------------------
extern "C" void kernel_launch(void* const* d_in, const int* in_sizes, int n_in,
                              void* d_out, int out_size, void* d_ws, size_t ws_size,
                              hipStream_t stream) {
    const float* x      = (const float*)d_in[0];
    const float* coords = (const float*)d_in[1];
    const float* Wq     = (const float*)d_in[2];
    const float* bq     = (const float*)d_in[3];
    const float* Wk     = (const float*)d_in[4];
    const float* bk     = (const float*)d_in[5];
    const float* Wv     = (const float*)d_in[6];
    const float* bv     = (const float*)d_in[7];
    const float* alpha  = (const float*)d_in[8];
    const float* W1     = (const float*)d_in[9];
    const float* b1     = (const float*)d_in[10];
    const float* W2     = (const float*)d_in[11];
    const float* b2     = (const float*)d_in[12];
    const float* g1     = (const float*)d_in[13];
    const float* be1    = (const float*)d_in[14];
    const float* g2     = (const float*)d_in[15];
    const float* be2    = (const float*)d_in[16];

    float* ws = (float*)d_ws;
    float*    xf    = ws;                             // 8 MB
    ushort_t* xb    = (ushort_t*)(ws + 2097152);      // 4 MB
    ushort_t* Qa    = (ushort_t*)(ws + 3145728);      // 8 MB [64 bh][1024][64]
    ushort_t* Ka    = (ushort_t*)(ws + 5242880);      // 8 MB
    ushort_t* Vt    = (ushort_t*)(ws + 7340032);      // 4 MB [64 bh][32][1024]
    float*    aout  = ws + 8388608;                   // 8 MB [8192][256]
    ushort_t* wqkvt = (ushort_t*)(ws + 10485760);     // 1.5 MB  [L][768][256]
    ushort_t* w1t   = (ushort_t*)(ws + 10878976);     // 2 MB    [L][1024][256]
    ushort_t* w2t   = (ushort_t*)(ws + 11403264);     // 2 MB    [L][256][1024]
    float*    bqkv  = ws + 11927552;                  // [L][768]

    ushort_t* hidden = Qa;      // [8192][1024] bf16 = 16 MB, spans Qa+Ka (dead in FFN phase)
    float*    ff2out = aout;    // aout dead after addln1

    // ---- fused weight prep (one dispatch) ----
    prep_kernel<<<NLAYERS * 707, 256, 0, stream>>>(Wq, Wk, Wv, W1, W2, bq, bk, bv,
                                                   wqkvt, w1t, w2t, bqkv);

    copy_in_kernel<<<ROW_ELEMS / 256, 256, 0, stream>>>(x, xf, xb, ROW_ELEMS);

    for (int i = 0; i < NLAYERS; ++i) {
        // fused QKV GEMM (64-row tiles) with scatter epilogue (+ coord dims) -> Qa, Ka, Vt
        mfma_gemm_kernel<2, 64><<<dim3(6, 128), 256, 0, stream>>>(
            xb, wqkvt + (size_t)i * 196608, bqkv + i * 768, Qa, Ka, Vt,
            coords, alpha, i, 256, 0);

        attn5_kernel<<<dim3(8, 8, 8), 256, 0, stream>>>(Qa, Ka, Vt, aout);

        addln_kernel<<<MM / 4, 256, 0, stream>>>(xf, xb, aout, 256, g1 + i * 256, be1 + i * 256, xf);

        // FF1: [8192,256]@[256,1024] + relu -> hidden bf16
        mfma_gemm_kernel<1, 128><<<dim3(8, 64), 256, 0, stream>>>(
            xb, w1t + (size_t)i * 262144, b1 + i * 1024, hidden, nullptr, nullptr,
            nullptr, nullptr, 0, 256, 1024);
        // FF2: [8192,1024]@[1024,256] -> ff2out f32 (64-row tiles for 256-block grid)
        mfma_gemm_kernel<0, 64><<<dim3(2, 128), 256, 0, stream>>>(
            hidden, w2t + (size_t)i * 262144, b2 + i * 256, ff2out, nullptr, nullptr,
            nullptr, nullptr, 0, 1024, 256);

        addln_kernel<<<MM / 4, 256, 0, stream>>>(xf, xb, ff2out, 256, g2 + i * 256, be2 + i * 256,
                                                 (i == NLAYERS - 1) ? (float*)d_out : xf);
    }
}

// Round 10
// 499.267 us; speedup vs baseline: 1.0077x; 1.0077x over previous
//
#include <hip/hip_runtime.h>
#include <hip/hip_bf16.h>

// Problem constants
#define BB 8
#define NN 1024
#define DD 256
#define HH 8
#define DK 32
#define FFN 1024
#define NLAYERS 4
#define MM (BB * NN)          // 8192 rows
#define ROW_ELEMS (MM * DD)   // 2,097,152

// 1/sqrt(32) * log2(e)  (log2e folded so attention uses native exp2)
#define QSCALE 0.2550655192922103f
#define LOG2E  1.4426950408889634f

typedef unsigned short ushort_t;
typedef __attribute__((ext_vector_type(8))) short bf16x8;
typedef __attribute__((ext_vector_type(4))) float f32x4;

__device__ __forceinline__ ushort_t f2b(float f) {
    __hip_bfloat16 h = __float2bfloat16(f);
    return *reinterpret_cast<ushort_t*>(&h);
}

// async global -> LDS, 16 B per lane. LDS dest = wave-uniform base + lane*16B.
__device__ __forceinline__ void async_ld16(const void* g, void* l) {
    __builtin_amdgcn_global_load_lds((const __attribute__((address_space(1))) void*)g,
                                     (__attribute__((address_space(3))) void*)l, 16, 0, 0);
}

// ---------------------------------------------------------------------------
// copy-in: x -> xf (f32) + xb (bf16)
// ---------------------------------------------------------------------------
__global__ __launch_bounds__(256) void copy_in_kernel(const float* __restrict__ in,
                                                      float* __restrict__ xf,
                                                      ushort_t* __restrict__ xb, int n) {
    int i = blockIdx.x * 256 + threadIdx.x;
    if (i < n) { float v = in[i]; xf[i] = v; xb[i] = f2b(v); }
}

// ---------------------------------------------------------------------------
// Fused weight prep (one dispatch): 5 transposes + bias concat.
// ---------------------------------------------------------------------------
__global__ __launch_bounds__(256) void prep_kernel(const float* __restrict__ Wq,
                                                   const float* __restrict__ Wk,
                                                   const float* __restrict__ Wv,
                                                   const float* __restrict__ W1,
                                                   const float* __restrict__ W2,
                                                   const float* __restrict__ bq,
                                                   const float* __restrict__ bk,
                                                   const float* __restrict__ bv,
                                                   ushort_t* __restrict__ wqkvt,
                                                   ushort_t* __restrict__ w1t,
                                                   ushort_t* __restrict__ w2t,
                                                   float* __restrict__ bqkv) {
    const int id = blockIdx.x;
    const int layer = id / 707;
    const int r = id % 707;
    const int tid = threadIdx.x;

    if (r >= 704) {  // bias concat: 3 chunks of 256
        const int chunk = r - 704;
        const float* src = (chunk == 0) ? bq : (chunk == 1) ? bk : bv;
        bqkv[layer * 768 + chunk * 256 + tid] = src[layer * 256 + tid];
        return;
    }

    const float* src;
    ushort_t* dst;
    int R, C, x, y;
    if (r < 192) {
        const int w = r >> 6, rr = r & 63;
        src = ((w == 0) ? Wq : (w == 1) ? Wk : Wv) + (size_t)layer * 65536;
        dst = wqkvt + (size_t)layer * 196608 + w * 65536;
        R = 256; C = 256; x = rr & 7; y = rr >> 3;
    } else if (r < 448) {
        const int rr = r - 192;
        src = W1 + (size_t)layer * 262144;
        dst = w1t + (size_t)layer * 262144;
        R = 256; C = 1024; x = rr & 31; y = rr >> 5;
    } else {
        const int rr = r - 448;
        src = W2 + (size_t)layer * 262144;
        dst = w2t + (size_t)layer * 262144;
        R = 1024; C = 256; x = rr & 7; y = rr >> 3;
    }
    const int r0 = y * 32, c0 = x * 32;
    __shared__ float tile[32][33];
    const int tx = tid & 31, ty = tid >> 5;
#pragma unroll
    for (int i = 0; i < 4; ++i)
        tile[ty + 8 * i][tx] = src[(size_t)(r0 + ty + 8 * i) * C + (c0 + tx)];
    __syncthreads();
#pragma unroll
    for (int i = 0; i < 4; ++i)
        dst[(size_t)(c0 + ty + 8 * i) * R + (r0 + tx)] = f2b(tile[tx][ty + 8 * i]);
}

// ---------------------------------------------------------------------------
// MFMA bf16 GEMM, async global_load_lds staging (16B).
// MODE 0: f32 out. MODE 1: relu + bf16 out. MODE 2: QKV scatter epilogue into
// Qa[bh][n][64] (x QSCALE, + alpha*log2e*coords in dims 32..34),
// Ka[bh][n][64] (+ coords in dims 32..34), Vt[bh][d][n] (packed ushort4).
// ---------------------------------------------------------------------------
template <int MODE, int BM>
__global__ __launch_bounds__(256) void mfma_gemm_kernel(const ushort_t* __restrict__ A,
                                                        const ushort_t* __restrict__ Bt,
                                                        const float* __restrict__ bias,
                                                        void* __restrict__ C0,
                                                        void* __restrict__ C1,
                                                        void* __restrict__ C2,
                                                        const float* __restrict__ coords,
                                                        const float* __restrict__ alpha, int layer,
                                                        int K, int ldc) {
    constexpr int NI = BM / 32;
    __shared__ ushort_t As[BM * 32];
    __shared__ ushort_t Bs[128 * 32];

    const int t    = threadIdx.x;
    const int bm   = blockIdx.y * BM;
    const int bn   = blockIdx.x * 128;
    const int wave = t >> 6, lane = t & 63;
    const int wm   = (wave >> 1) * (BM / 2), wn = (wave & 1) * 64;
    const int quad = lane >> 4, l16 = lane & 15;

    const int srow = t >> 2;
    const int scol = (t & 3) * 8;

    f32x4 acc[NI][4];
#pragma unroll
    for (int i = 0; i < NI; ++i)
#pragma unroll
        for (int j = 0; j < 4; ++j) {
            f32x4 z = {0.f, 0.f, 0.f, 0.f};
            acc[i][j] = z;
        }

    for (int k0 = 0; k0 < K; k0 += 32) {
        __syncthreads();
        async_ld16(A + (size_t)(bm + srow) * K + k0 + scol, As + wave * 512);
        if constexpr (BM == 128)
            async_ld16(A + (size_t)(bm + 64 + srow) * K + k0 + scol, As + 2048 + wave * 512);
        async_ld16(Bt + (size_t)(bn + srow) * K + k0 + scol, Bs + wave * 512);
        async_ld16(Bt + (size_t)(bn + 64 + srow) * K + k0 + scol, Bs + 2048 + wave * 512);
        __syncthreads();

        bf16x8 af[NI], bfr[4];
#pragma unroll
        for (int i = 0; i < NI; ++i)
            af[i] = *(const bf16x8*)(As + (wm + i * 16 + l16) * 32 + quad * 8);
#pragma unroll
        for (int j = 0; j < 4; ++j)
            bfr[j] = *(const bf16x8*)(Bs + (wn + j * 16 + l16) * 32 + quad * 8);
#pragma unroll
        for (int i = 0; i < NI; ++i)
#pragma unroll
            for (int j = 0; j < 4; ++j)
                acc[i][j] = __builtin_amdgcn_mfma_f32_16x16x32_bf16(af[i], bfr[j], acc[i][j], 0, 0, 0);
    }

    const float av = (MODE == 2) ? alpha[layer] : 0.f;

#pragma unroll
    for (int j = 0; j < 4; ++j) {
        const int col = bn + wn + j * 16 + l16;
        const float bsv = bias[col];
#pragma unroll
        for (int i = 0; i < NI; ++i) {
            const int row0 = bm + wm + i * 16 + quad * 4;
            if (MODE == 2) {
                const int bb2 = row0 >> 10, nn0 = row0 & 1023;
                const int which = col >> 8, rem = col & 255;
                const int h = rem >> 5, d = rem & 31;
                const size_t bh = (size_t)((bb2 << 3) + h);
                if (which == 2) {
                    ushort4 pk;
                    pk.x = f2b(acc[i][j][0] + bsv);
                    pk.y = f2b(acc[i][j][1] + bsv);
                    pk.z = f2b(acc[i][j][2] + bsv);
                    pk.w = f2b(acc[i][j][3] + bsv);
                    *(ushort4*)&((ushort_t*)C2)[(bh * DK + d) * NN + nn0] = pk;
                } else {
#pragma unroll
                    for (int r = 0; r < 4; ++r) {
                        const float v = acc[i][j][r] + bsv;
                        const int nn = nn0 + r;
                        if (which == 0) {
                            ((ushort_t*)C0)[(bh * NN + nn) * 64 + d] = f2b(v * QSCALE);
                            ushort_t ext = 0;
                            if (d < 3) ext = f2b(av * LOG2E * coords[(size_t)(bb2 * NN + nn) * 3 + d]);
                            ((ushort_t*)C0)[(bh * NN + nn) * 64 + 32 + d] = ext;
                        } else {
                            ((ushort_t*)C1)[(bh * NN + nn) * 64 + d] = f2b(v);
                            ushort_t ext = 0;
                            if (d < 3) ext = f2b(coords[(size_t)(bb2 * NN + nn) * 3 + d]);
                            ((ushort_t*)C1)[(bh * NN + nn) * 64 + 32 + d] = ext;
                        }
                    }
                }
            } else {
#pragma unroll
                for (int r = 0; r < 4; ++r) {
                    float v = acc[i][j][r] + bsv;
                    if (MODE == 0)
                        ((float*)C0)[(size_t)(row0 + r) * ldc + col] = v;
                    else
                        ((ushort_t*)C0)[(size_t)(row0 + r) * ldc + col] = f2b(fmaxf(v, 0.f));
                }
            }
        }
    }
}

// ---------------------------------------------------------------------------
// MFMA flash attention v4 — wave-private key-split + S^T softmax path.
// Grid (8,8,8), block 256 = 4 waves; wave w owns disjoint keys [w*256,+256).
// Scores computed TRANSPOSED (A=Ka, B=Qa -> D[key][q]), so each lane's 4
// C-regs are 4 consecutive keys of one q-row: exp2 (log2e pre-folded into Qa)
// + pack -> ONE ds_write_b64 per jt (4 writes/subtile vs 16 scalar). PV reads
// P back in A-frag layout via ds_read_b128 (unchanged). No-max softmax
// (scores O(1), validated rounds 4-9). Final 4-way merge through LDS.
// ---------------------------------------------------------------------------
__global__ __launch_bounds__(256, 2) void attn6_kernel(const ushort_t* __restrict__ Qa,
                                                       const ushort_t* __restrict__ Ka,
                                                       const ushort_t* __restrict__ Vt,
                                                       float* __restrict__ aout) {
    const int b = blockIdx.z, h = blockIdx.y, n0 = blockIdx.x * 128;
    const int t = threadIdx.x, wave = t >> 6, lane = t & 63;
    const int quad = lane >> 4, l16 = lane & 15;
    const int bh = b * HH + h;

    __shared__ __align__(16) char smem[75776];
    ushort_t (*Ks)[64][72]    = (ushort_t (*)[64][72])smem;              // [4] 36864 B
    ushort_t (*Vs)[32][72]    = (ushort_t (*)[32][72])(smem + 36864);    // [4] 18432 B
    ushort_t (*Ps)[2][16][72] = (ushort_t (*)[2][16][72])(smem + 55296); // [4] 18432 B
    float    (*Om)[128][36]   = (float (*)[128][36])smem;                // [4] merge alias
    float    (*Lm)[128]       = (float (*)[128])(smem + 73728);          // 2048 B

    // Q fragments: 8 subtiles of 16 q-rows (whole block's 128 q, per wave)
    bf16x8 aq[8][2];
#pragma unroll
    for (int s = 0; s < 8; ++s) {
        const ushort_t* qp = Qa + ((size_t)bh * NN + n0 + s * 16 + l16) * 64 + quad * 8;
        aq[s][0] = *(const bf16x8*)qp;
        aq[s][1] = *(const bf16x8*)(qp + 32);
    }

    bf16x8 ones;
#pragma unroll
    for (int i = 0; i < 8; ++i) ones[i] = (short)0x3F80;  // bf16 1.0

    const f32x4 z = {0.f, 0.f, 0.f, 0.f};
    f32x4 acc_o0[8], acc_o1[8], acc_l[8];
#pragma unroll
    for (int s = 0; s < 8; ++s) { acc_o0[s] = z; acc_o1[s] = z; acc_l[s] = z; }

    const ushort_t* kg = Ka + ((size_t)bh * NN + wave * 256) * 64;
    const ushort_t* vg = Vt + (size_t)bh * DK * NN + wave * 256;

    const int srow = lane >> 3, sch = (lane & 7) * 8;   // staging: 8 rows x 8 chunks

    for (int kt = 0; kt < 4; ++kt) {
        // stage this wave's 64-key K tile (64x64) and V tile (32x64) privately
#pragma unroll
        for (int i = 0; i < 8; ++i) {
            uint4 kv = *(const uint4*)(kg + (size_t)(kt * 64 + i * 8 + srow) * 64 + sch);
            *(uint4*)&Ks[wave][i * 8 + srow][sch] = kv;
        }
#pragma unroll
        for (int i = 0; i < 4; ++i) {
            uint4 vv = *(const uint4*)(vg + (size_t)(i * 8 + srow) * NN + kt * 64 + sch);
            *(uint4*)&Vs[wave][i * 8 + srow][sch] = vv;
        }
        __builtin_amdgcn_s_waitcnt(0xC07F);   // lgkmcnt(0): staging writes visible
        __builtin_amdgcn_wave_barrier();

        bf16x8 bk0[4], bk1[4];
#pragma unroll
        for (int jt = 0; jt < 4; ++jt) {
            bk0[jt] = *(const bf16x8*)&Ks[wave][jt * 16 + l16][quad * 8];
            bk1[jt] = *(const bf16x8*)&Ks[wave][jt * 16 + l16][32 + quad * 8];
        }
        bf16x8 bv00 = *(const bf16x8*)&Vs[wave][l16][quad * 8];
        bf16x8 bv01 = *(const bf16x8*)&Vs[wave][l16][32 + quad * 8];
        bf16x8 bv10 = *(const bf16x8*)&Vs[wave][16 + l16][quad * 8];
        bf16x8 bv11 = *(const bf16x8*)&Vs[wave][16 + l16][32 + quad * 8];

#pragma unroll
        for (int s = 0; s < 8; ++s) {
            const int pb = s & 1;
            // S^T: A=Ka frag, B=Qa frag -> D[row=key (quad*4+r), col=q (l16)]
            f32x4 st[4];
#pragma unroll
            for (int jt = 0; jt < 4; ++jt) {
                st[jt] = __builtin_amdgcn_mfma_f32_16x16x32_bf16(bk0[jt], aq[s][0], z, 0, 0, 0);
                st[jt] = __builtin_amdgcn_mfma_f32_16x16x32_bf16(bk1[jt], aq[s][1], st[jt], 0, 0, 0);
            }
            // P[q=l16][key]: 4 consecutive keys per (jt) -> one b64 write each
#pragma unroll
            for (int jt = 0; jt < 4; ++jt) {
                float e0 = exp2f(st[jt][0]);
                float e1 = exp2f(st[jt][1]);
                float e2 = exp2f(st[jt][2]);
                float e3 = exp2f(st[jt][3]);
                uint2 pk;
                pk.x = (unsigned int)f2b(e0) | ((unsigned int)f2b(e1) << 16);
                pk.y = (unsigned int)f2b(e2) | ((unsigned int)f2b(e3) << 16);
                *(uint2*)&Ps[wave][pb][l16][jt * 16 + quad * 4] = pk;
            }

            __builtin_amdgcn_s_waitcnt(0xC07F);   // lgkmcnt(0): P writes visible
            __builtin_amdgcn_wave_barrier();

            bf16x8 pa0 = *(const bf16x8*)&Ps[wave][pb][l16][quad * 8];
            bf16x8 pa1 = *(const bf16x8*)&Ps[wave][pb][l16][32 + quad * 8];

            acc_o0[s] = __builtin_amdgcn_mfma_f32_16x16x32_bf16(pa0, bv00, acc_o0[s], 0, 0, 0);
            acc_o0[s] = __builtin_amdgcn_mfma_f32_16x16x32_bf16(pa1, bv01, acc_o0[s], 0, 0, 0);
            acc_o1[s] = __builtin_amdgcn_mfma_f32_16x16x32_bf16(pa0, bv10, acc_o1[s], 0, 0, 0);
            acc_o1[s] = __builtin_amdgcn_mfma_f32_16x16x32_bf16(pa1, bv11, acc_o1[s], 0, 0, 0);
            acc_l[s]  = __builtin_amdgcn_mfma_f32_16x16x32_bf16(pa0, ones, acc_l[s], 0, 0, 0);
            acc_l[s]  = __builtin_amdgcn_mfma_f32_16x16x32_bf16(pa1, ones, acc_l[s], 0, 0, 0);
        }
    }

    // ---- merge the 4 waves' disjoint-key partials ----
    __syncthreads();   // all waves done with Ks/Vs/Ps; re-alias as Om/Lm
#pragma unroll
    for (int s = 0; s < 8; ++s)
#pragma unroll
        for (int r = 0; r < 4; ++r) {
            const int q = s * 16 + quad * 4 + r;
            Om[wave][q][l16]      = acc_o0[s][r];
            Om[wave][q][16 + l16] = acc_o1[s][r];
            if (l16 == 0) Lm[wave][q] = acc_l[s][r];
        }
    __syncthreads();

    {
        const int q = t >> 1, dh = (t & 1) * 16;
        float l = Lm[0][q] + Lm[1][q] + Lm[2][q] + Lm[3][q];
        const float inv = 1.0f / l;
        float* op = aout + (size_t)(b * NN + n0 + q) * DD + h * DK + dh;
#pragma unroll
        for (int c = 0; c < 4; ++c) {
            float4 acc4 = {0.f, 0.f, 0.f, 0.f};
#pragma unroll
            for (int w = 0; w < 4; ++w) {
                float4 v = *(const float4*)&Om[w][q][dh + c * 4];
                acc4.x += v.x; acc4.y += v.y; acc4.z += v.z; acc4.w += v.w;
            }
            float4 o = {acc4.x * inv, acc4.y * inv, acc4.z * inv, acc4.w * inv};
            *(float4*)(op + c * 4) = o;
        }
    }
}

// ---------------------------------------------------------------------------
// xout = LayerNorm(x + delta) * g + be ; also writes bf16 xb.
// ---------------------------------------------------------------------------
__global__ __launch_bounds__(256) void addln_kernel(const float* __restrict__ x,
                                                    ushort_t* __restrict__ xb,
                                                    const float* __restrict__ delta, int dstride,
                                                    const float* __restrict__ g,
                                                    const float* __restrict__ be,
                                                    float* __restrict__ xout) {
    const int row  = blockIdx.x * 4 + (threadIdx.x >> 6);
    const int lane = threadIdx.x & 63;
    const size_t base = (size_t)row * DD + lane * 4;

    float4 xv = *(const float4*)(x + base);
    float4 dl = *(const float4*)(delta + (size_t)row * dstride + lane * 4);
    float v0 = xv.x + dl.x, v1 = xv.y + dl.y, v2 = xv.z + dl.z, v3 = xv.w + dl.w;

    float s = v0 + v1 + v2 + v3;
#pragma unroll
    for (int off = 32; off; off >>= 1) s += __shfl_xor(s, off);
    const float mean = s * (1.0f / 256.0f);

    float d0 = v0 - mean, d1 = v1 - mean, d2 = v2 - mean, d3 = v3 - mean;
    float s2 = d0 * d0 + d1 * d1 + d2 * d2 + d3 * d3;
#pragma unroll
    for (int off = 32; off; off >>= 1) s2 += __shfl_xor(s2, off);
    const float rs = rsqrtf(s2 * (1.0f / 256.0f) + 1e-5f);

    float4 gv = *(const float4*)(g + lane * 4);
    float4 bv = *(const float4*)(be + lane * 4);
    float y0 = d0 * rs * gv.x + bv.x;
    float y1 = d1 * rs * gv.y + bv.y;
    float y2 = d2 * rs * gv.z + bv.z;
    float y3 = d3 * rs * gv.w + bv.w;

    float4 o = {y0, y1, y2, y3};
    *(float4*)(xout + base) = o;
    ushort4 ob = {f2b(y0), f2b(y1), f2b(y2), f2b(y3)};
    *(ushort4*)(xb + base) = ob;
}

// ---------------------------------------------------------------------------
// launch — workspace ~45.5 MB
// ---------------------------------------------------------------------------
extern "C" void kernel_launch(void* const* d_in, const int* in_sizes, int n_in,
                              void* d_out, int out_size, void* d_ws, size_t ws_size,
                              hipStream_t stream) {
    const float* x      = (const float*)d_in[0];
    const float* coords = (const float*)d_in[1];
    const float* Wq     = (const float*)d_in[2];
    const float* bq     = (const float*)d_in[3];
    const float* Wk     = (const float*)d_in[4];
    const float* bk     = (const float*)d_in[5];
    const float* Wv     = (const float*)d_in[6];
    const float* bv     = (const float*)d_in[7];
    const float* alpha  = (const float*)d_in[8];
    const float* W1     = (const float*)d_in[9];
    const float* b1     = (const float*)d_in[10];
    const float* W2     = (const float*)d_in[11];
    const float* b2     = (const float*)d_in[12];
    const float* g1     = (const float*)d_in[13];
    const float* be1    = (const float*)d_in[14];
    const float* g2     = (const float*)d_in[15];
    const float* be2    = (const float*)d_in[16];

    float* ws = (float*)d_ws;
    float*    xf    = ws;                             // 8 MB
    ushort_t* xb    = (ushort_t*)(ws + 2097152);      // 4 MB
    ushort_t* Qa    = (ushort_t*)(ws + 3145728);      // 8 MB [64 bh][1024][64]
    ushort_t* Ka    = (ushort_t*)(ws + 5242880);      // 8 MB
    ushort_t* Vt    = (ushort_t*)(ws + 7340032);      // 4 MB [64 bh][32][1024]
    float*    aout  = ws + 8388608;                   // 8 MB [8192][256]
    ushort_t* wqkvt = (ushort_t*)(ws + 10485760);     // 1.5 MB  [L][768][256]
    ushort_t* w1t   = (ushort_t*)(ws + 10878976);     // 2 MB    [L][1024][256]
    ushort_t* w2t   = (ushort_t*)(ws + 11403264);     // 2 MB    [L][256][1024]
    float*    bqkv  = ws + 11927552;                  // [L][768]

    ushort_t* hidden = Qa;      // [8192][1024] bf16 = 16 MB, spans Qa+Ka (dead in FFN phase)
    float*    ff2out = aout;    // aout dead after addln1

    // ---- fused weight prep (one dispatch) ----
    prep_kernel<<<NLAYERS * 707, 256, 0, stream>>>(Wq, Wk, Wv, W1, W2, bq, bk, bv,
                                                   wqkvt, w1t, w2t, bqkv);

    copy_in_kernel<<<ROW_ELEMS / 256, 256, 0, stream>>>(x, xf, xb, ROW_ELEMS);

    for (int i = 0; i < NLAYERS; ++i) {
        // fused QKV GEMM (64-row tiles) with scatter epilogue (+ coord dims) -> Qa, Ka, Vt
        mfma_gemm_kernel<2, 64><<<dim3(6, 128), 256, 0, stream>>>(
            xb, wqkvt + (size_t)i * 196608, bqkv + i * 768, Qa, Ka, Vt,
            coords, alpha, i, 256, 0);

        attn6_kernel<<<dim3(8, 8, 8), 256, 0, stream>>>(Qa, Ka, Vt, aout);

        addln_kernel<<<MM / 4, 256, 0, stream>>>(xf, xb, aout, 256, g1 + i * 256, be1 + i * 256, xf);

        // FF1: [8192,256]@[256,1024] + relu -> hidden bf16
        mfma_gemm_kernel<1, 128><<<dim3(8, 64), 256, 0, stream>>>(
            xb, w1t + (size_t)i * 262144, b1 + i * 1024, hidden, nullptr, nullptr,
            nullptr, nullptr, 0, 256, 1024);
        // FF2: [8192,1024]@[1024,256] -> ff2out f32 (64-row tiles for 256-block grid)
        mfma_gemm_kernel<0, 64><<<dim3(2, 128), 256, 0, stream>>>(
            hidden, w2t + (size_t)i * 262144, b2 + i * 256, ff2out, nullptr, nullptr,
            nullptr, nullptr, 0, 1024, 256);

        addln_kernel<<<MM / 4, 256, 0, stream>>>(xf, xb, ff2out, 256, g2 + i * 256, be2 + i * 256,
                                                 (i == NLAYERS - 1) ? (float*)d_out : xf);
    }
}